// Round 1
// baseline (822.806 us; speedup 1.0000x reference)
//
#include <hip/hip_runtime.h>

#define NH  12
#define DH  64
#define SEQ 2048
#define NB  2
#define EMB 768

typedef float f32x4 __attribute__((ext_vector_type(4)));
typedef short s16x8 __attribute__((ext_vector_type(8)));

static __device__ __forceinline__ unsigned short f2bf(float f) {
    union { float f; unsigned u; } x; x.f = f;
    unsigned r = x.u + 0x7fffu + ((x.u >> 16) & 1u);   // RNE
    return (unsigned short)(r >> 16);
}

// ---------------------------------------------------------------------------
// Projection: Y[s, o] = sum_e X[s, e] * W[o, e]   (NT GEMM, K=768)
// mode 0: q  -> [B,H,S,D] bf16, scaled by 0.125
// mode 1: k  -> [B,H,S,D] bf16
// mode 2: vT -> [B,H,D,S] bf16 (transposed for PV B-operand)
// ---------------------------------------------------------------------------
__global__ __launch_bounds__(256) void proj_kernel(
    const float* __restrict__ X, const float* __restrict__ W,
    unsigned short* __restrict__ out, int mode) {
    __shared__ unsigned short lA[64][40];   // 64 rows x 32 k, +8 pad (80B rows, 16B aligned)
    __shared__ unsigned short lB[64][40];

    const int t    = threadIdx.x;
    const int lane = t & 63;
    const int w    = t >> 6;
    const int m0   = blockIdx.x * 64;
    const int n0   = blockIdx.y * 64;

    const int lrow = t >> 2;          // 0..63
    const int lkc  = (t & 3) * 8;     // 0,8,16,24
    const float* xs = X + (size_t)(m0 + lrow) * EMB + lkc;
    const float* ws = W + (size_t)(n0 + lrow) * EMB + lkc;

    const int fr = lane & 15;
    const int fo = (lane >> 4) * 8;

    f32x4 acc[4] = {};

    for (int k0 = 0; k0 < EMB; k0 += 32) {
        float4 a0 = *(const float4*)(xs + k0);
        float4 a1 = *(const float4*)(xs + k0 + 4);
        float4 b0 = *(const float4*)(ws + k0);
        float4 b1 = *(const float4*)(ws + k0 + 4);
        __syncthreads();   // previous iter's MFMA reads done
        s16x8 av, bv;
        av[0]=(short)f2bf(a0.x); av[1]=(short)f2bf(a0.y); av[2]=(short)f2bf(a0.z); av[3]=(short)f2bf(a0.w);
        av[4]=(short)f2bf(a1.x); av[5]=(short)f2bf(a1.y); av[6]=(short)f2bf(a1.z); av[7]=(short)f2bf(a1.w);
        bv[0]=(short)f2bf(b0.x); bv[1]=(short)f2bf(b0.y); bv[2]=(short)f2bf(b0.z); bv[3]=(short)f2bf(b0.w);
        bv[4]=(short)f2bf(b1.x); bv[5]=(short)f2bf(b1.y); bv[6]=(short)f2bf(b1.z); bv[7]=(short)f2bf(b1.w);
        *(s16x8*)&lA[lrow][lkc] = av;
        *(s16x8*)&lB[lrow][lkc] = bv;
        __syncthreads();
        s16x8 af = *(const s16x8*)&lA[w * 16 + fr][fo];
#pragma unroll
        for (int cg = 0; cg < 4; ++cg) {
            s16x8 bf = *(const s16x8*)&lB[cg * 16 + fr][fo];
            acc[cg] = __builtin_amdgcn_mfma_f32_16x16x32_bf16(af, bf, acc[cg], 0, 0, 0);
        }
    }

    const int fg = lane >> 4;
#pragma unroll
    for (int cg = 0; cg < 4; ++cg) {
#pragma unroll
        for (int i = 0; i < 4; ++i) {
            int m = m0 + w * 16 + fg * 4 + i;   // global row (b*S + s)
            int n = n0 + cg * 16 + fr;          // global col (h*D + d)
            float v = acc[cg][i];
            if (mode == 0) v *= 0.125f;         // 1/sqrt(64)
            int b = m >> 11, s = m & 2047;
            int h = n >> 6,  d = n & 63;
            size_t idx;
            if (mode == 2) idx = ((size_t)(b * NH + h) * DH + d) * SEQ + s;
            else           idx = ((size_t)(b * NH + h) * SEQ + s) * DH + d;
            out[idx] = f2bf(v);
        }
    }
}

// ---------------------------------------------------------------------------
// Attention: per block = one (b,h) x 64 q-rows.  4 waves x 16 rows each.
// Sweep 1: scores = q k^T (MFMA), store raw fp32 into attn region, online (m,l).
// Sweep 2: read scores back (L2), attn = exp(s-m)/l (masked -> 0), write,
//          PV accumulate via MFMA with vT tile staged in LDS.
// ---------------------------------------------------------------------------
__global__ __launch_bounds__(256) void attn_kernel(
    const unsigned short* __restrict__ Q, const unsigned short* __restrict__ K,
    const unsigned short* __restrict__ VT, const int* __restrict__ mask,
    float* __restrict__ out0, float* __restrict__ attn) {
    __shared__ unsigned short lT[64][72];   // K-tile [t][d] or vT-tile [d][t]; 144B rows
    __shared__ float sm[64], sl[64];

    const int t    = threadIdx.x;
    const int lane = t & 63;
    const int w    = t >> 6;
    const int qt = blockIdx.x, h = blockIdx.y, b = blockIdx.z;
    const int bh = b * NH + h;

    const unsigned short* Qb = Q  + (size_t)bh * SEQ * DH;
    const unsigned short* Kb = K  + (size_t)bh * SEQ * DH;
    const unsigned short* Vb = VT + (size_t)bh * DH * SEQ;
    const int* mk = mask + b * SEQ;
    float* attnb = attn + (size_t)bh * SEQ * SEQ;

    const int q0 = qt * 64 + w * 16;
    const int fr = lane & 15;
    const int fg = lane >> 4;

    // Q fragments (held all kernel): row = q0 + fr, k(d) = fg*8..+8 (+32)
    s16x8 qa0 = *(const s16x8*)(Qb + (size_t)(q0 + fr) * DH + fg * 8);
    s16x8 qa1 = *(const s16x8*)(Qb + (size_t)(q0 + fr) * DH + 32 + fg * 8);

    float m[4], l[4];
#pragma unroll
    for (int i = 0; i < 4; ++i) { m[i] = -INFINITY; l[i] = 0.f; }

    const int crow = t >> 2;          // 0..63
    const int cc   = (t & 3) * 16;    // 0,16,32,48 (ushort units)

    // ---------------- sweep 1: scores + online softmax stats ----------------
    for (int t0 = 0; t0 < SEQ; t0 += 64) {
        const uint4* src = (const uint4*)(Kb + (size_t)(t0 + crow) * DH + cc);
        uint4 d0 = src[0], d1 = src[1];
        __syncthreads();
        *(uint4*)&lT[crow][cc]     = d0;
        *(uint4*)&lT[crow][cc + 8] = d1;
        __syncthreads();
#pragma unroll
        for (int tt = 0; tt < 4; ++tt) {
            s16x8 kb0 = *(const s16x8*)&lT[tt * 16 + fr][fg * 8];
            s16x8 kb1 = *(const s16x8*)&lT[tt * 16 + fr][32 + fg * 8];
            f32x4 sc = {};
            sc = __builtin_amdgcn_mfma_f32_16x16x32_bf16(qa0, kb0, sc, 0, 0, 0);
            sc = __builtin_amdgcn_mfma_f32_16x16x32_bf16(qa1, kb1, sc, 0, 0, 0);
            const int tg = t0 + tt * 16 + fr;
            const int mv = mk[tg];
            float* arow = attnb + (size_t)(q0 + fg * 4) * SEQ + tg;
#pragma unroll
            for (int i = 0; i < 4; ++i) {
                float s = sc[i];
                arow[(size_t)i * SEQ] = s;                 // raw score
                float se = mv ? -INFINITY : s;
                float mn = fmaxf(m[i], se);
                float alpha = (m[i] == mn) ? 1.f : __expf(m[i] - mn);
                float p = (se == -INFINITY) ? 0.f : __expf(se - mn);
                l[i] = l[i] * alpha + p;
                m[i] = mn;
            }
        }
    }

    // reduce (m,l) across the 16 lanes of each group
#pragma unroll
    for (int i = 0; i < 4; ++i) {
#pragma unroll
        for (int off = 1; off < 16; off <<= 1) {
            float om = __shfl_xor(m[i], off);
            float ol = __shfl_xor(l[i], off);
            float mn = fmaxf(m[i], om);
            float ea = (m[i] == mn) ? 1.f : __expf(m[i] - mn);
            float eb = (om   == mn) ? 1.f : __expf(om   - mn);
            l[i] = l[i] * ea + ol * eb;
            m[i] = mn;
        }
    }
    if (fr == 0) {
#pragma unroll
        for (int i = 0; i < 4; ++i) {
            sm[w * 16 + fg * 4 + i] = m[i];
            sl[w * 16 + fg * 4 + i] = l[i];
        }
    }
    __syncthreads();

    const float rm  = sm[w * 16 + fr];                 // row = q0 + fr
    const float rls = sl[w * 16 + fr];
    const float rl  = rls > 0.f ? 1.f / rls : 0.f;

    f32x4 acc[4] = {};

    // ---------------- sweep 2: attn write + PV ----------------
    for (int t0 = 0; t0 < SEQ; t0 += 64) {
        const uint4* src = (const uint4*)(Vb + (size_t)crow * SEQ + t0 + cc);
        uint4 d0 = src[0], d1 = src[1];
        __syncthreads();
        *(uint4*)&lT[crow][cc]     = d0;   // lT[d][t-chunk]
        *(uint4*)&lT[crow][cc + 8] = d1;
        __syncthreads();
#pragma unroll
        for (int ks = 0; ks < 2; ++ks) {
            const int tb = t0 + ks * 32 + fg * 8;
            float* prow = attnb + (size_t)(q0 + fr) * SEQ + tb;
            float4 s0v = *(const float4*)prow;
            float4 s1v = *(const float4*)(prow + 4);
            int4 mv0 = *(const int4*)(mk + tb);
            int4 mv1 = *(const int4*)(mk + tb + 4);
            float4 p0, p1;
            p0.x = mv0.x ? 0.f : __expf(s0v.x - rm) * rl;
            p0.y = mv0.y ? 0.f : __expf(s0v.y - rm) * rl;
            p0.z = mv0.z ? 0.f : __expf(s0v.z - rm) * rl;
            p0.w = mv0.w ? 0.f : __expf(s0v.w - rm) * rl;
            p1.x = mv1.x ? 0.f : __expf(s1v.x - rm) * rl;
            p1.y = mv1.y ? 0.f : __expf(s1v.y - rm) * rl;
            p1.z = mv1.z ? 0.f : __expf(s1v.z - rm) * rl;
            p1.w = mv1.w ? 0.f : __expf(s1v.w - rm) * rl;
            *(float4*)prow       = p0;                 // final attn values
            *(float4*)(prow + 4) = p1;
            s16x8 af;
            af[0]=(short)f2bf(p0.x); af[1]=(short)f2bf(p0.y); af[2]=(short)f2bf(p0.z); af[3]=(short)f2bf(p0.w);
            af[4]=(short)f2bf(p1.x); af[5]=(short)f2bf(p1.y); af[6]=(short)f2bf(p1.z); af[7]=(short)f2bf(p1.w);
#pragma unroll
            for (int dg = 0; dg < 4; ++dg) {
                s16x8 bf = *(const s16x8*)&lT[dg * 16 + fr][ks * 32 + fg * 8];
                acc[dg] = __builtin_amdgcn_mfma_f32_16x16x32_bf16(af, bf, acc[dg], 0, 0, 0);
            }
        }
    }

    // epilogue: out0[b, s=q0+row, h*64 + dg*16 + fr]
    float* outp = out0 + ((size_t)b * SEQ + q0 + fg * 4) * EMB + h * DH;
#pragma unroll
    for (int dg = 0; dg < 4; ++dg) {
#pragma unroll
        for (int i = 0; i < 4; ++i) {
            outp[(size_t)i * EMB + dg * 16 + fr] = acc[dg][i];
        }
    }
}

extern "C" void kernel_launch(void* const* d_in, const int* in_sizes, int n_in,
                              void* d_out, int out_size, void* d_ws, size_t ws_size,
                              hipStream_t stream) {
    const float* query = (const float*)d_in[0];
    const float* key   = (const float*)d_in[1];
    const float* value = (const float*)d_in[2];
    const int*   kpm   = (const int*)d_in[3];
    const float* Wq    = (const float*)d_in[4];
    const float* Wk    = (const float*)d_in[5];
    const float* Wv    = (const float*)d_in[6];

    float* out  = (float*)d_out;
    float* attn = out + (size_t)NB * SEQ * EMB;   // output 1 region

    const size_t per = (size_t)NB * NH * SEQ * DH;   // 3,145,728 elements
    unsigned short* qb = (unsigned short*)d_ws;
    unsigned short* kb = qb + per;
    unsigned short* vt = kb + per;

    dim3 pgrid(64, 12, 1);   // M=4096 / 64, N=768 / 64
    proj_kernel<<<pgrid, 256, 0, stream>>>(query, Wq, qb, 0);
    proj_kernel<<<pgrid, 256, 0, stream>>>(key,   Wk, kb, 1);
    proj_kernel<<<pgrid, 256, 0, stream>>>(value, Wv, vt, 2);

    dim3 agrid(SEQ / 64, NH, NB);
    attn_kernel<<<agrid, 256, 0, stream>>>(qb, kb, vt, kpm, out, attn);
}

// Round 3
// 560.488 us; speedup vs baseline: 1.4680x; 1.4680x over previous
//
#include <hip/hip_runtime.h>

#define NH  12
#define DH  64
#define SEQ 2048
#define NB  2
#define EMB 768

typedef float f32x4 __attribute__((ext_vector_type(4)));
typedef short s16x8 __attribute__((ext_vector_type(8)));

static __device__ __forceinline__ unsigned short f2bf(float f) {
    union { float f; unsigned u; } x; x.f = f;
    unsigned r = x.u + 0x7fffu + ((x.u >> 16) & 1u);   // RNE
    return (unsigned short)(r >> 16);
}

// exp2 via hardware v_exp_f32 (scores are pre-scaled by log2(e))
static __device__ __forceinline__ float fexp2(float x) {
#if __has_builtin(__builtin_amdgcn_exp2f)
    return __builtin_amdgcn_exp2f(x);
#else
    return __expf(x * 0.6931471805599453f);
#endif
}

// ---------------------------------------------------------------------------
// Convert fp32 -> bf16: z=0..2: X inputs (3.145M each), z=3..5: W (589k each)
// ---------------------------------------------------------------------------
__global__ __launch_bounds__(256) void convert_kernel(
    const float* __restrict__ s0, const float* __restrict__ s1,
    const float* __restrict__ s2, const float* __restrict__ s3,
    const float* __restrict__ s4, const float* __restrict__ s5,
    unsigned short* __restrict__ dst) {
    const int z = blockIdx.y;
    const float* src = (z == 0) ? s0 : (z == 1) ? s1 : (z == 2) ? s2
                     : (z == 3) ? s3 : (z == 4) ? s4 : s5;
    const size_t nx = (size_t)4096 * 768;          // 3145728
    const size_t nw = (size_t)768 * 768;           // 589824
    const size_t n   = (z < 3) ? nx : nw;
    const size_t off = (z < 3) ? (size_t)z * nx : 3 * nx + (size_t)(z - 3) * nw;
    size_t i = ((size_t)blockIdx.x * 256 + threadIdx.x) * 8;
    if (i >= n) return;
    float4 a = *(const float4*)(src + i);
    float4 b = *(const float4*)(src + i + 4);
    s16x8 o;
    o[0]=(short)f2bf(a.x); o[1]=(short)f2bf(a.y); o[2]=(short)f2bf(a.z); o[3]=(short)f2bf(a.w);
    o[4]=(short)f2bf(b.x); o[5]=(short)f2bf(b.y); o[6]=(short)f2bf(b.z); o[7]=(short)f2bf(b.w);
    *(s16x8*)(dst + off + i) = o;
}

// ---------------------------------------------------------------------------
// Projection GEMM (bf16 in, bf16 out): Y[s,o] = sum_e X[s,e] W[o,e]
// blockIdx.z = mode: 0: q (scaled by 0.125*log2e) -> [B,H,S,D]
//                    1: k -> [B,H,S,D]    2: vT -> [B,H,D,S]
// 128x64 tile, BK=32, 4 waves x (32 rows x 64 cols)
// ---------------------------------------------------------------------------
__global__ __launch_bounds__(256) void proj_kernel(
    const unsigned short* __restrict__ Xall, const unsigned short* __restrict__ Wall,
    unsigned short* __restrict__ Oall) {
    __shared__ unsigned short lA[128][40];
    __shared__ unsigned short lB[64][40];

    const int t    = threadIdx.x;
    const int lane = t & 63;
    const int w    = t >> 6;
    const int m0   = blockIdx.x * 128;
    const int n0   = blockIdx.y * 64;
    const int mode = blockIdx.z;

    const unsigned short* X = Xall + (size_t)mode * 4096 * 768;
    const unsigned short* W = Wall + (size_t)mode * 768 * 768;
    unsigned short* out     = Oall + (size_t)mode * 4096 * 768;

    // A staging: thread t covers row t>>1, k-chunks (t&1)*16 and +8 (16 shorts)
    const int ar = t >> 1;
    const int ac = (t & 1) * 16;
    // B staging: thread t covers row t>>2, k-chunk (t&3)*8 (8 shorts)
    const int br = t >> 2;
    const int bc = (t & 3) * 8;

    const unsigned short* xs = X + (size_t)(m0 + ar) * EMB + ac;
    const unsigned short* ws = W + (size_t)(n0 + br) * EMB + bc;

    const int fr = lane & 15;
    const int fg = lane >> 4;

    f32x4 acc[2][4] = {};

    for (int k0 = 0; k0 < EMB; k0 += 32) {
        uint4 a0 = *(const uint4*)(xs + k0);
        uint4 a1 = *(const uint4*)(xs + k0 + 8);
        uint4 b0 = *(const uint4*)(ws + k0);
        __syncthreads();
        *(uint4*)&lA[ar][ac]     = a0;
        *(uint4*)&lA[ar][ac + 8] = a1;
        *(uint4*)&lB[br][bc]     = b0;
        __syncthreads();
        s16x8 af0 = *(const s16x8*)&lA[w * 32 + fr][fg * 8];
        s16x8 af1 = *(const s16x8*)&lA[w * 32 + 16 + fr][fg * 8];
#pragma unroll
        for (int cg = 0; cg < 4; ++cg) {
            s16x8 bf = *(const s16x8*)&lB[cg * 16 + fr][fg * 8];
            acc[0][cg] = __builtin_amdgcn_mfma_f32_16x16x32_bf16(af0, bf, acc[0][cg], 0, 0, 0);
            acc[1][cg] = __builtin_amdgcn_mfma_f32_16x16x32_bf16(af1, bf, acc[1][cg], 0, 0, 0);
        }
    }

#pragma unroll
    for (int mi = 0; mi < 2; ++mi) {
#pragma unroll
        for (int cg = 0; cg < 4; ++cg) {
#pragma unroll
            for (int i = 0; i < 4; ++i) {
                int m = m0 + w * 32 + mi * 16 + fg * 4 + i;   // b*S+s
                int n = n0 + cg * 16 + fr;                    // h*D+d
                float v = acc[mi][cg][i];
                if (mode == 0) v *= 0.18033688011112042f;     // 0.125 * log2(e)
                int b = m >> 11, s = m & 2047;
                int h = n >> 6,  d = n & 63;
                size_t idx;
                if (mode == 2) idx = ((size_t)(b * NH + h) * DH + d) * SEQ + s;
                else           idx = ((size_t)(b * NH + h) * SEQ + s) * DH + d;
                out[idx] = f2bf(v);
            }
        }
    }
}

// ---------------------------------------------------------------------------
// Attention: block = (qtile of 64 rows, h, b). 4 waves x 16 q-rows.
// Pass 1: QK^T MFMA -> online (m,l) stats only (exp2 units, defer-max). No stores.
// Pass 2: recompute QK^T, p = exp2(s - m) / l (masked -> 0), single fp32 write
//         to attn, bf16 p via wave-local LDS transpose -> PV MFMA.
// ---------------------------------------------------------------------------
__global__ __launch_bounds__(256) void attn_kernel(
    const unsigned short* __restrict__ Q, const unsigned short* __restrict__ K,
    const unsigned short* __restrict__ VT, const int* __restrict__ mask,
    float* __restrict__ out0, float* __restrict__ attn) {
    __shared__ unsigned short lK[64][72];
    __shared__ unsigned short lV[64][72];
    __shared__ unsigned short pP[64][72];
    __shared__ float bias[SEQ];
    __shared__ float sm[64], sl[64];

    const int t    = threadIdx.x;
    const int lane = t & 63;
    const int w    = t >> 6;

    // XCD-aware swizzle: 768 blocks, 8 XCDs, 96 contiguous per XCD
    int wg  = blockIdx.x + 32 * (blockIdx.y + 12 * blockIdx.z);
    int swz = (wg & 7) * 96 + (wg >> 3);
    const int qt = swz & 31;
    const int h  = (swz >> 5) % 12;
    const int b  = swz / (32 * 12);
    const int bh = b * NH + h;

    const unsigned short* Qb = Q  + (size_t)bh * SEQ * DH;
    const unsigned short* Kb = K  + (size_t)bh * SEQ * DH;
    const unsigned short* Vb = VT + (size_t)bh * DH * SEQ;
    float* attnb = attn + (size_t)bh * SEQ * SEQ;

    const int* mk = mask + b * SEQ;
    for (int i = t; i < SEQ; i += 256) bias[i] = mk[i] ? -30000.f : 0.f;

    const int q0 = qt * 64 + w * 16;
    const int fr = lane & 15;
    const int fg = lane >> 4;

    s16x8 qa0 = *(const s16x8*)(Qb + (size_t)(q0 + fr) * DH + fg * 8);
    s16x8 qa1 = *(const s16x8*)(Qb + (size_t)(q0 + fr) * DH + 32 + fg * 8);

    float m[4], l[4];
#pragma unroll
    for (int i = 0; i < 4; ++i) { m[i] = -1e30f; l[i] = 0.f; }

    const int crow = t >> 2;
    const int cc   = (t & 3) * 16;

    // ---------------- pass 1: stats only ----------------
    for (int t0 = 0; t0 < SEQ; t0 += 64) {
        const uint4* src = (const uint4*)(Kb + (size_t)(t0 + crow) * DH + cc);
        uint4 d0 = src[0], d1 = src[1];
        __syncthreads();
        *(uint4*)&lK[crow][cc]     = d0;
        *(uint4*)&lK[crow][cc + 8] = d1;
        __syncthreads();
#pragma unroll
        for (int tt = 0; tt < 4; ++tt) {
            s16x8 kb0 = *(const s16x8*)&lK[tt * 16 + fr][fg * 8];
            s16x8 kb1 = *(const s16x8*)&lK[tt * 16 + fr][32 + fg * 8];
            f32x4 sc = {};
            sc = __builtin_amdgcn_mfma_f32_16x16x32_bf16(qa0, kb0, sc, 0, 0, 0);
            sc = __builtin_amdgcn_mfma_f32_16x16x32_bf16(qa1, kb1, sc, 0, 0, 0);
            float bt = bias[t0 + tt * 16 + fr];
            float s4[4], mn[4];
#pragma unroll
            for (int i = 0; i < 4; ++i) { s4[i] = sc[i] + bt; mn[i] = fmaxf(m[i], s4[i]); }
            float g = fmaxf(fmaxf(mn[0] - m[0], mn[1] - m[1]),
                            fmaxf(mn[2] - m[2], mn[3] - m[3]));
            if (g > 8.f) {
#pragma unroll
                for (int i = 0; i < 4; ++i) { l[i] *= fexp2(m[i] - mn[i]); m[i] = mn[i]; }
            }
#pragma unroll
            for (int i = 0; i < 4; ++i) l[i] += fexp2(s4[i] - m[i]);
        }
    }

    // reduce (m,l) across the 16 lanes of each fg-group (consecutive lanes)
#pragma unroll
    for (int i = 0; i < 4; ++i) {
#pragma unroll
        for (int off = 1; off < 16; off <<= 1) {
            float om = __shfl_xor(m[i], off);
            float ol = __shfl_xor(l[i], off);
            float mn = fmaxf(m[i], om);
            l[i] = l[i] * fexp2(m[i] - mn) + ol * fexp2(om - mn);
            m[i] = mn;
        }
    }
    if (fr == 0) {
#pragma unroll
        for (int i = 0; i < 4; ++i) {
            sm[w * 16 + fg * 4 + i] = m[i];
            sl[w * 16 + fg * 4 + i] = l[i];
        }
    }
    __syncthreads();

    float rmv[4], rlv[4];
#pragma unroll
    for (int i = 0; i < 4; ++i) {
        rmv[i] = sm[w * 16 + fg * 4 + i];
        float lv = sl[w * 16 + fg * 4 + i];
        rlv[i] = lv > 0.f ? 1.f / lv : 0.f;
    }

    f32x4 acc[4] = {};

    // ---------------- pass 2: write attn + PV ----------------
    for (int t0 = 0; t0 < SEQ; t0 += 64) {
        const uint4* ksrc = (const uint4*)(Kb + (size_t)(t0 + crow) * DH + cc);
        const uint4* vsrc = (const uint4*)(Vb + (size_t)crow * SEQ + t0 + cc);
        uint4 k0v = ksrc[0], k1v = ksrc[1];
        uint4 v0v = vsrc[0], v1v = vsrc[1];
        __syncthreads();
        *(uint4*)&lK[crow][cc]     = k0v;
        *(uint4*)&lK[crow][cc + 8] = k1v;
        *(uint4*)&lV[crow][cc]     = v0v;
        *(uint4*)&lV[crow][cc + 8] = v1v;
        __syncthreads();
#pragma unroll
        for (int tt = 0; tt < 4; ++tt) {
            s16x8 kb0 = *(const s16x8*)&lK[tt * 16 + fr][fg * 8];
            s16x8 kb1 = *(const s16x8*)&lK[tt * 16 + fr][32 + fg * 8];
            f32x4 sc = {};
            sc = __builtin_amdgcn_mfma_f32_16x16x32_bf16(qa0, kb0, sc, 0, 0, 0);
            sc = __builtin_amdgcn_mfma_f32_16x16x32_bf16(qa1, kb1, sc, 0, 0, 0);
            float bt = bias[t0 + tt * 16 + fr];
            float* ap = attnb + (size_t)(q0 + fg * 4) * SEQ + (t0 + tt * 16 + fr);
#pragma unroll
            for (int i = 0; i < 4; ++i) {
                float p = fexp2(sc[i] + bt - rmv[i]) * rlv[i];
                ap[(size_t)i * SEQ] = p;
                pP[w * 16 + fg * 4 + i][tt * 16 + fr] = f2bf(p);
            }
        }
        // wave-local transpose readback (same-wave LDS dep: compiler waits lgkmcnt)
#pragma unroll
        for (int ks2 = 0; ks2 < 2; ++ks2) {
            s16x8 af = *(const s16x8*)&pP[w * 16 + fr][ks2 * 32 + fg * 8];
#pragma unroll
            for (int dg = 0; dg < 4; ++dg) {
                s16x8 bf = *(const s16x8*)&lV[dg * 16 + fr][ks2 * 32 + fg * 8];
                acc[dg] = __builtin_amdgcn_mfma_f32_16x16x32_bf16(af, bf, acc[dg], 0, 0, 0);
            }
        }
    }

    float* outp = out0 + ((size_t)b * SEQ + q0 + fg * 4) * EMB + h * DH;
#pragma unroll
    for (int dg = 0; dg < 4; ++dg) {
#pragma unroll
        for (int i = 0; i < 4; ++i) {
            outp[(size_t)i * EMB + dg * 16 + fr] = acc[dg][i];
        }
    }
}

extern "C" void kernel_launch(void* const* d_in, const int* in_sizes, int n_in,
                              void* d_out, int out_size, void* d_ws, size_t ws_size,
                              hipStream_t stream) {
    const float* query = (const float*)d_in[0];
    const float* key   = (const float*)d_in[1];
    const float* value = (const float*)d_in[2];
    const int*   kpm   = (const int*)d_in[3];
    const float* Wq    = (const float*)d_in[4];
    const float* Wk    = (const float*)d_in[5];
    const float* Wv    = (const float*)d_in[6];

    float* out  = (float*)d_out;
    float* attn = out + (size_t)NB * SEQ * EMB;

    const size_t nx = (size_t)4096 * 768;   // per X array
    const size_t nw = (size_t)768 * 768;    // per W array

    unsigned short* xbf = (unsigned short*)d_ws;       // 3 * nx
    unsigned short* wbf = xbf + 3 * nx;                // 3 * nw
    unsigned short* qkv = wbf + 3 * nw;                // 3 * nx (q, k, vT)

    convert_kernel<<<dim3(1536, 6), 256, 0, stream>>>(query, key, value, Wq, Wk, Wv, xbf);
    proj_kernel<<<dim3(32, 12, 3), 256, 0, stream>>>(xbf, wbf, qkv);

    const unsigned short* qb = qkv;
    const unsigned short* kb = qkv + nx;
    const unsigned short* vt = qkv + 2 * nx;
    attn_kernel<<<dim3(32, 12, 2), 256, 0, stream>>>(qb, kb, vt, kpm, out, attn);
}